// Round 2
// baseline (5760.225 us; speedup 1.0000x reference)
//
#include <hip/hip_runtime.h>
#include <stdint.h>

typedef __attribute__((ext_vector_type(4))) int i32x4;
typedef unsigned short u16;
typedef unsigned char u8;

#define QMAX 32512.0f

__device__ __forceinline__ float bf2f(u16 u) {
    union { uint32_t i; float f; } v; v.i = ((uint32_t)u) << 16; return v.f;
}
__device__ __forceinline__ u16 f2bf(float f) {
    union { float f; uint32_t i; } v; v.f = f;
    uint32_t r = v.i + 0x7fffu + ((v.i >> 16) & 1u);
    return (u16)(r >> 16);
}
__device__ __forceinline__ float sigf(float x) { return 1.0f / (1.0f + __expf(-x)); }
__device__ __forceinline__ i32x4 mfma8(i32x4 a, i32x4 b, i32x4 c) {
    return __builtin_amdgcn_mfma_i32_16x16x64_i8(a, b, c, 0, 0, 0);
}
__device__ __forceinline__ void qsplit(float v, float s, int& hi, int& lo) {
    float q = fminf(fmaxf(v * s, -QMAX), QMAX);
    int qi = (int)rintf(q);
    lo = ((qi + 128) & 255) - 128;
    hi = (qi - lo) >> 8;
}

// ---------------- per-column max |U|, |W|
__global__ __launch_bounds__(256) void scale_kernel(
    const float* __restrict__ U0, const float* __restrict__ U1,
    const float* __restrict__ U2, const float* __restrict__ U3,
    const float* __restrict__ W0, const float* __restrict__ W1,
    const float* __restrict__ W2, const float* __restrict__ W3,
    float* __restrict__ Uscale, float* __restrict__ Wscale)
{
    int idx = blockIdx.x * 256 + threadIdx.x;
    if (idx < 4096) {
        int l = idx >> 10, col = idx & 1023;
        const float* U = (l==0)?U0:(l==1)?U1:(l==2)?U2:U3;
        float m = 0.f;
        for (int k = 0; k < 256; ++k) m = fmaxf(m, fabsf(U[k*1024 + col]));
        Uscale[idx] = m;
    } else if (idx < 8192) {
        int j = idx - 4096;
        int l = j >> 10, col = j & 1023;
        const float* W = (l==0)?W0:(l==1)?W1:(l==2)?W2:W3;
        const int F = (l==0)?80:(l==1)?64:(l==2)?48:32;
        float m = 0.f;
        for (int k = 0; k < F; ++k) m = fmaxf(m, fabsf(W[k*1024 + col]));
        Wscale[j] = m;
    }
}

// ---------------- pack U,W to i8 hi/lo in MFMA-fragment order
// Upk per lstm 512KB: [cb 64][kt 4][half 2][lane 64][16B]; col=cb*16+(lane&15), k=kt*64+16*(lane>>4)+i
// Wpk per lstm 256KB: [cb 64][kt8 2][half 2][lane 64][16B]; k=kt8*64+16*(lane>>4)+i, zero-pad k>=F
__global__ __launch_bounds__(256) void pack_kernel(
    const float* __restrict__ U0, const float* __restrict__ U1,
    const float* __restrict__ U2, const float* __restrict__ U3,
    const float* __restrict__ W0, const float* __restrict__ W1,
    const float* __restrict__ W2, const float* __restrict__ W3,
    const float* __restrict__ Uscale, const float* __restrict__ Wscale,
    u8* __restrict__ Upk, u8* __restrict__ Wpk)
{
    int idx = blockIdx.x * 256 + threadIdx.x;      // one u32 (4 bytes) per thread
    const int NU4 = 524288;                         // 2MB/4
    const int NW4 = 262144;                         // 1MB/4
    if (idx < NU4) {
        int byte = idx * 4;
        int l = byte >> 19; int off = byte & 524287;
        int cb = off >> 13; int r1 = off & 8191;
        int kt = r1 >> 11;  int r2 = r1 & 2047;
        int half = r2 >> 10; int lb = r2 & 1023;
        int lane = lb >> 4;  int i0 = lb & 15;
        const float* U = (l==0)?U0:(l==1)?U1:(l==2)?U2:U3;
        int col = cb*16 + (lane & 15);
        float s = QMAX / fmaxf(Uscale[l*1024 + col], 1e-30f);
        uint32_t w = 0;
        for (int j = 0; j < 4; ++j) {
            int k = kt*64 + (lane >> 4)*16 + i0 + j;
            int hi, lo; qsplit(U[k*1024 + col], s, hi, lo);
            int b = half ? lo : hi;
            w |= ((uint32_t)(b & 255)) << (8*j);
        }
        ((uint32_t*)Upk)[idx] = w;
    } else if (idx < NU4 + NW4) {
        int j4 = idx - NU4;
        int byte = j4 * 4;
        int l = byte >> 18; int off = byte & 262143;
        int cb = off >> 12; int r1 = off & 4095;
        int kt8 = r1 >> 11; int r2 = r1 & 2047;
        int half = r2 >> 10; int lb = r2 & 1023;
        int lane = lb >> 4;  int i0 = lb & 15;
        const float* W = (l==0)?W0:(l==1)?W1:(l==2)?W2:W3;
        const int F = (l==0)?80:(l==1)?64:(l==2)?48:32;
        int col = cb*16 + (lane & 15);
        float s = QMAX / fmaxf(Wscale[l*1024 + col], 1e-30f);
        uint32_t w = 0;
        for (int j = 0; j < 4; ++j) {
            int k = kt8*64 + (lane >> 4)*16 + i0 + j;
            float v = (k < F) ? W[k*1024 + col] : 0.f;
            int hi, lo; qsplit(v, s, hi, lo);
            int b = half ? lo : hi;
            w |= ((uint32_t)(b & 255)) << (8*j);
        }
        ((uint32_t*)Wpk)[j4] = w;
    }
}

// ---------------- quantize x rows to i8 hi/lo (pre-swizzled), rowmax + mask
// xq per lstm: [b 128][t 256][half 2][128B]; byte pos in row = ((slot^ (b&7))<<4)|(k&15), slot=k>>4
template<int F>
__global__ __launch_bounds__(256) void xq_kernel(
    const float* __restrict__ xin, u8* __restrict__ xq,
    float* __restrict__ xsc, u8* __restrict__ maskb, int lstm)
{
    int b = blockIdx.x, t = threadIdx.x;
    const float* row = xin + ((size_t)b*256 + t)*F;
    float xv[F];
    float m = 0.f; bool any = false;
#pragma unroll
    for (int f4 = 0; f4 < F/4; ++f4) {
        float4 v = ((const float4*)row)[f4];
        xv[4*f4+0]=v.x; xv[4*f4+1]=v.y; xv[4*f4+2]=v.z; xv[4*f4+3]=v.w;
        m = fmaxf(m, fmaxf(fmaxf(fabsf(v.x),fabsf(v.y)),fmaxf(fabsf(v.z),fabsf(v.w))));
        any = any || (v.x != -1.f) || (v.y != -1.f) || (v.z != -1.f) || (v.w != -1.f);
    }
    float s = QMAX / fmaxf(m, 1e-30f);
    size_t base = ((size_t)(lstm*128 + b)*256 + t) * 256;   // 2 halves * 128B
    int r7 = b & 7;
#pragma unroll
    for (int f4 = 0; f4 < 32; ++f4) {
        uint32_t wh = 0, wl = 0;
#pragma unroll
        for (int j = 0; j < 4; ++j) {
            int f = 4*f4 + j;
            float v = (f < F) ? xv[f] : 0.f;
            int hi, lo; qsplit(v, s, hi, lo);
            wh |= ((uint32_t)(hi & 255)) << (8*j);
            wl |= ((uint32_t)(lo & 255)) << (8*j);
        }
        int f0 = 4*f4; int slot = f0 >> 4;
        int pos = ((slot ^ r7) << 4) | (f0 & 15);
        *(uint32_t*)(xq + base + pos)       = wh;
        *(uint32_t*)(xq + base + 128 + pos) = wl;
    }
    xsc[(lstm*128 + b)*256 + t] = m;
    maskb[(lstm*128 + b)*256 + t] = any ? 1 : 0;
}

// ---------------- recurrence: 32 WGs (4 lstm x 8 row-blocks of 16), 512 thr (8 waves)
__global__ __launch_bounds__(512, 2) void lstm_rec_kernel(
    const u8* __restrict__ Upk_all, const u8* __restrict__ Wpk_all,
    const u8* __restrict__ xq, const float* __restrict__ xsc_g,
    const u8* __restrict__ maskb,
    const float* __restrict__ Uscale, const float* __restrict__ Wscale,
    const float* __restrict__ bb0, const float* __restrict__ bb1,
    const float* __restrict__ bb2, const float* __restrict__ bb3,
    u16* __restrict__ merged)
{
    const int lstm = blockIdx.x >> 3;
    const int b0 = (blockIdx.x & 7) * 16;
    const int tid = threadIdx.x;
    const int w = tid >> 6, l = tid & 63, lg = l >> 4, ln = l & 15;

    const u8* Ub = Upk_all + (size_t)lstm * 524288;
    const u8* Wb = Wpk_all + (size_t)lstm * 262144;
    const float* bias = (lstm==0)?bb0:(lstm==1)?bb1:(lstm==2)?bb2:bb3;

    __shared__ u8 qA[2][2][16][256];     // [buf][half][row][swizzled k] : 16KB
    __shared__ u8 qX[2][2][16][128];     // 8KB
    __shared__ u8 mask_l[16][256];       // 4KB
    __shared__ float xsc_l[16][256];     // 16KB
    __shared__ float wmax[16][8];        // [row][wave]

    // preload mask + xsc; zero qA
    for (int i = tid; i < 1024; i += 512)
        ((uint32_t*)mask_l)[i] = *(const uint32_t*)(maskb + (size_t)lstm*32768 + b0*256 + i*4);
    for (int i = tid; i < 4096; i += 512)
        ((float*)xsc_l)[i] = xsc_g[(size_t)lstm*32768 + b0*256 + i];
    for (int i = tid; i < 4096; i += 512)
        ((uint32_t*)qA)[i] = 0;

    // qX staging assignment (2 u32 per thread per step)
    int sh[2], sr[2], sj[2];
    const u8* sbase[2];
    for (int j = 0; j < 2; ++j) {
        int c = tid + j*512;                 // 0..1023
        sh[j] = c >> 9; sr[j] = (c >> 5) & 15; sj[j] = c & 31;
        sbase[j] = xq + ((size_t)(lstm*128 + b0 + sr[j])*256)*256 + sh[j]*128 + sj[j]*4;
    }
    // stage t=0
    for (int j = 0; j < 2; ++j)
        ((uint32_t*)&qX[0][sh[j]][sr[j]][0])[sj[j]] = *(const uint32_t*)(sbase[j]);
    __syncthreads();

    const int u0 = 32*w + ln, u1 = u0 + 16;
    float bv[4][2], cU[8], cW[8];
#pragma unroll
    for (int g = 0; g < 4; ++g) {
        bv[g][0] = bias[256*g + u0];
        bv[g][1] = bias[256*g + u1];
    }
#pragma unroll
    for (int ti = 0; ti < 8; ++ti) {
        int g = ti >> 1, m = ti & 1;
        int col = g*256 + 32*w + 16*m + ln;
        const float inv2 = 1.0f / (QMAX * QMAX);
        cU[ti] = Uscale[lstm*1024 + col] * inv2;
        cW[ti] = Wscale[lstm*1024 + col] * inv2;
    }

    float c_[2][4] = {{0,0,0,0},{0,0,0,0}};
    float h_[2][4] = {{0,0,0,0},{0,0,0,0}};
    float rmaxh[4] = {0,0,0,0};
    const i32x4 zero4 = {0,0,0,0};

    for (int t = 0; t < 256; ++t) {
        const int cur = t & 1, nxt = cur ^ 1;

        // prefetch next x tile
        uint32_t pf[2];
        if (t + 1 < 256) {
            pf[0] = *(const uint32_t*)(sbase[0] + (size_t)(t+1)*256);
            pf[1] = *(const uint32_t*)(sbase[1] + (size_t)(t+1)*256);
        }

        // ---- W phase: z_x = x @ W
        i32x4 axh[2], axl[2];
#pragma unroll
        for (int k8 = 0; k8 < 2; ++k8) {
            int slot = (k8*4 + lg) ^ (ln & 7);
            axh[k8] = *(const i32x4*)&qX[cur][0][ln][slot*16];
            axl[k8] = *(const i32x4*)&qX[cur][1][ln][slot*16];
        }
        i32x4 ah[8], ax[8];
#pragma unroll
        for (int ti = 0; ti < 8; ++ti) { ah[ti] = zero4; ax[ti] = zero4; }
#pragma unroll
        for (int ti = 0; ti < 8; ++ti) {
            int g = ti >> 1, m = ti & 1;
            int cb = g*16 + 2*w + m;
#pragma unroll
            for (int k8 = 0; k8 < 2; ++k8) {
                const u8* p = Wb + ((size_t)(cb*2 + k8)*2)*1024 + l*16;
                i32x4 bh = *(const i32x4*)p;
                i32x4 bl = *(const i32x4*)(p + 1024);
                ah[ti] = mfma8(axh[k8], bh, ah[ti]);
                ax[ti] = mfma8(axh[k8], bl, ax[ti]);
                ax[ti] = mfma8(axl[k8], bh, ax[ti]);
            }
        }
        float z[8][4];
#pragma unroll
        for (int ti = 0; ti < 8; ++ti)
#pragma unroll
            for (int rg = 0; rg < 4; ++rg) {
                int r = lg*4 + rg;
                z[ti][rg] = (65536.f*(float)ah[ti][rg] + 256.f*(float)ax[ti][rg])
                            * cW[ti] * xsc_l[r][t];
            }

        // ---- U phase: h @ U
        i32x4 aah[4], aal[4];
#pragma unroll
        for (int kt = 0; kt < 4; ++kt) {
            int slot = (kt*4 + lg) ^ ln;
            aah[kt] = *(const i32x4*)&qA[cur][0][ln][slot*16];
            aal[kt] = *(const i32x4*)&qA[cur][1][ln][slot*16];
        }
#pragma unroll
        for (int ti = 0; ti < 8; ++ti) { ah[ti] = zero4; ax[ti] = zero4; }
#pragma unroll
        for (int ti = 0; ti < 8; ++ti) {
            int g = ti >> 1, m = ti & 1;
            int cb = g*16 + 2*w + m;
#pragma unroll
            for (int kt = 0; kt < 4; ++kt) {
                const u8* p = Ub + ((size_t)(cb*4 + kt)*2)*1024 + l*16;
                i32x4 bh = *(const i32x4*)p;
                i32x4 bl = *(const i32x4*)(p + 1024);
                ah[ti] = mfma8(aah[kt], bh, ah[ti]);
                ax[ti] = mfma8(aah[kt], bl, ax[ti]);
                ax[ti] = mfma8(aal[kt], bh, ax[ti]);
            }
        }

        // ---- epilogue: gates, state update, merged write
        float vmax[4];
#pragma unroll
        for (int rg = 0; rg < 4; ++rg) {
            const int r = lg*4 + rg;
            const int mk = mask_l[r][t];
            const float dq = rmaxh[rg];
#pragma unroll
            for (int m = 0; m < 2; ++m) {
                const int u = (m == 0) ? u0 : u1;
                float zi = z[0+m][rg] + (65536.f*(float)ah[0+m][rg] + 256.f*(float)ax[0+m][rg])*cU[0+m]*dq + bv[0][m];
                float zf = z[2+m][rg] + (65536.f*(float)ah[2+m][rg] + 256.f*(float)ax[2+m][rg])*cU[2+m]*dq + bv[1][m];
                float zg = z[4+m][rg] + (65536.f*(float)ah[4+m][rg] + 256.f*(float)ax[4+m][rg])*cU[4+m]*dq + bv[2][m];
                float zo = z[6+m][rg] + (65536.f*(float)ah[6+m][rg] + 256.f*(float)ax[6+m][rg])*cU[6+m]*dq + bv[3][m];
                float ig = sigf(zi), fg = sigf(zf), og = sigf(zo);
                float gg = fmaxf(zg, 0.f);
                float cn = fg * c_[m][rg] + ig * gg;
                float hn = og * fmaxf(cn, 0.f);
                if (!mk) { cn = c_[m][rg]; hn = h_[m][rg]; }
                c_[m][rg] = cn; h_[m][rg] = hn;
                merged[((size_t)(b0 + r)*256 + t)*1024 + lstm*256 + u] = f2bf(hn);
            }
            vmax[rg] = fmaxf(h_[0][rg], h_[1][rg]);   // h >= 0
        }
        // wave-local row max (16-lane groups share lg -> same 4 rows)
#pragma unroll
        for (int rg = 0; rg < 4; ++rg) {
            float v = vmax[rg];
            v = fmaxf(v, __shfl_xor(v, 1));
            v = fmaxf(v, __shfl_xor(v, 2));
            v = fmaxf(v, __shfl_xor(v, 4));
            v = fmaxf(v, __shfl_xor(v, 8));
            if (ln == 0) wmax[lg*4 + rg][w] = v;
        }
        __syncthreads();   // B1: wmax complete; all qA[cur]/qX[cur] reads done

        // per-thread row max over 8 waves; quantize own h into qA[nxt]
#pragma unroll
        for (int rg = 0; rg < 4; ++rg) {
            const int r = lg*4 + rg;
            float4 p0 = *(const float4*)&wmax[r][0];
            float4 p1 = *(const float4*)&wmax[r][4];
            float rm = fmaxf(fmaxf(fmaxf(p0.x,p0.y),fmaxf(p0.z,p0.w)),
                             fmaxf(fmaxf(p1.x,p1.y),fmaxf(p1.z,p1.w)));
            rmaxh[rg] = rm;
            float qs = QMAX / fmaxf(rm, 1e-30f);
#pragma unroll
            for (int m = 0; m < 2; ++m) {
                const int u = (m == 0) ? u0 : u1;
                int hi, lo; qsplit(h_[m][rg], qs, hi, lo);
                int pos = (((u >> 4) ^ r) << 4) | (u & 15);
                qA[nxt][0][r][pos] = (u8)hi;
                qA[nxt][1][r][pos] = (u8)lo;
            }
        }
        // stage qX[nxt]
        if (t + 1 < 256) {
            ((uint32_t*)&qX[nxt][sh[0]][sr[0]][0])[sj[0]] = pf[0];
            ((uint32_t*)&qX[nxt][sh[1]][sr[1]][0])[sj[1]] = pf[1];
        }
        __syncthreads();   // B2: qA[nxt]/qX[nxt] ready
    }
}

// ---------------- attention + output head: one WG per batch row
__global__ __launch_bounds__(256) void attn_kernel(
    const u16* __restrict__ merged,
    const float* __restrict__ w_att, const float* __restrict__ b_att,
    const float* __restrict__ w_out, const float* __restrict__ b_out,
    float* __restrict__ out)
{
    const int b = blockIdx.x;
    const int tid = threadIdx.x;
    const int wv = tid >> 6;
    const int l = tid & 63;

    __shared__ float watt_s[1024];
    __shared__ float wout_s[1024];
    __shared__ float sc[256];
    __shared__ float red[8];

    for (int i = tid; i < 1024; i += 256) {
        watt_s[i] = w_att[i];
        wout_s[i] = w_out[i];
    }
    __syncthreads();

    const float batt = b_att[0];

    for (int tt = wv; tt < 256; tt += 4) {
        const u16* row = merged + ((size_t)b * 256 + tt) * 1024 + l * 16;
        uint4 q0 = *(const uint4*)(row);
        uint4 q1 = *(const uint4*)(row + 8);
        const float* wp = &watt_s[l * 16];
        uint32_t qa[8] = {q0.x, q0.y, q0.z, q0.w, q1.x, q1.y, q1.z, q1.w};
        float s = 0.f;
#pragma unroll
        for (int i = 0; i < 8; ++i) {
            s += bf2f((u16)(qa[i] & 0xffffu)) * wp[2 * i];
            s += bf2f((u16)(qa[i] >> 16)) * wp[2 * i + 1];
        }
#pragma unroll
        for (int o = 32; o > 0; o >>= 1) s += __shfl_xor(s, o);
        if (l == 0) sc[tt] = tanhf(s + batt);
    }
    __syncthreads();

    float v = sc[tid];
    float mx = v;
#pragma unroll
    for (int o = 32; o > 0; o >>= 1) mx = fmaxf(mx, __shfl_xor(mx, o));
    if (l == 0) red[wv] = mx;
    __syncthreads();
    mx = fmaxf(fmaxf(red[0], red[1]), fmaxf(red[2], red[3]));
    float p = __expf(v - mx);
    float sm = p;
#pragma unroll
    for (int o = 32; o > 0; o >>= 1) sm += __shfl_xor(sm, o);
    if (l == 0) red[4 + wv] = sm;
    __syncthreads();
    sm = red[4] + red[5] + red[6] + red[7];
    p /= sm;
    sc[tid] = p;
    __syncthreads();

    const int d0 = tid * 4;
    float a0 = 0.f, a1 = 0.f, a2 = 0.f, a3 = 0.f;
    for (int t = 0; t < 256; ++t) {
        float pp = sc[t];
        const u16* mp = merged + ((size_t)b * 256 + t) * 1024 + d0;
        ushort4 q = *(const ushort4*)mp;
        a0 += pp * bf2f(q.x);
        a1 += pp * bf2f(q.y);
        a2 += pp * bf2f(q.z);
        a3 += pp * bf2f(q.w);
    }
    float part = a0 * wout_s[d0] + a1 * wout_s[d0 + 1] + a2 * wout_s[d0 + 2] + a3 * wout_s[d0 + 3];
#pragma unroll
    for (int o = 32; o > 0; o >>= 1) part += __shfl_xor(part, o);
    __syncthreads();
    if (l == 0) red[wv] = part;
    __syncthreads();
    if (tid == 0) {
        float tot = red[0] + red[1] + red[2] + red[3] + b_out[0];
        out[b] = 1.0f / (1.0f + __expf(-tot));
    }
}

extern "C" void kernel_launch(void* const* d_in, const int* in_sizes, int n_in,
                              void* d_out, int out_size, void* d_ws, size_t ws_size,
                              hipStream_t stream) {
    (void)in_sizes; (void)n_in; (void)out_size; (void)ws_size;
    const float* x[4]; const float* W[4]; const float* U[4]; const float* bb[4];
    for (int i = 0; i < 4; ++i) {
        x[i]  = (const float*)d_in[4 * i + 0];
        W[i]  = (const float*)d_in[4 * i + 1];
        U[i]  = (const float*)d_in[4 * i + 2];
        bb[i] = (const float*)d_in[4 * i + 3];
    }
    const float* w_att = (const float*)d_in[16];
    const float* b_att = (const float*)d_in[17];
    const float* w_out = (const float*)d_in[18];
    const float* b_out = (const float*)d_in[19];

    // ws layout
    u8* base = (u8*)d_ws;
    u16*  merged = (u16*)base;                       // 67,108,864 B
    u8*   xq     = base + 67108864;                  // 33,554,432 B
    u8*   Upk    = base + 100663296;                 //  2,097,152 B
    u8*   Wpk    = base + 102760448;                 //  1,048,576 B
    float* Uscale = (float*)(base + 103809024);      //     16,384 B
    float* Wscale = (float*)(base + 103825408);      //     16,384 B
    float* xsc    = (float*)(base + 103841792);      //    524,288 B
    u8*   maskb  = base + 104366080;                 //    131,072 B

    scale_kernel<<<dim3(32), dim3(256), 0, stream>>>(
        U[0], U[1], U[2], U[3], W[0], W[1], W[2], W[3], Uscale, Wscale);
    pack_kernel<<<dim3(3072), dim3(256), 0, stream>>>(
        U[0], U[1], U[2], U[3], W[0], W[1], W[2], W[3], Uscale, Wscale, Upk, Wpk);
    xq_kernel<80><<<dim3(128), dim3(256), 0, stream>>>(x[0], xq, xsc, maskb, 0);
    xq_kernel<64><<<dim3(128), dim3(256), 0, stream>>>(x[1], xq, xsc, maskb, 1);
    xq_kernel<48><<<dim3(128), dim3(256), 0, stream>>>(x[2], xq, xsc, maskb, 2);
    xq_kernel<32><<<dim3(128), dim3(256), 0, stream>>>(x[3], xq, xsc, maskb, 3);
    lstm_rec_kernel<<<dim3(32), dim3(512), 0, stream>>>(
        Upk, Wpk, xq, xsc, maskb, Uscale, Wscale,
        bb[0], bb[1], bb[2], bb[3], merged);
    attn_kernel<<<dim3(128), dim3(256), 0, stream>>>(
        merged, w_att, b_att, w_out, b_out, (float*)d_out);
}

// Round 3
// 4164.115 us; speedup vs baseline: 1.3833x; 1.3833x over previous
//
#include <hip/hip_runtime.h>
#include <stdint.h>

typedef __attribute__((ext_vector_type(4))) int   i32x4;
typedef __attribute__((ext_vector_type(4))) float f32x4;
typedef __attribute__((ext_vector_type(8))) short bf16x8;
typedef unsigned short u16;
typedef unsigned char  u8;

#define QMAX 32512.0f
#define ZSCL 2047.0f

__device__ __forceinline__ float bf2f(u16 u) {
    union { uint32_t i; float f; } v; v.i = ((uint32_t)u) << 16; return v.f;
}
__device__ __forceinline__ u16 f2bf(float f) {
    union { float f; uint32_t i; } v; v.f = f;
    uint32_t r = v.i + 0x7fffu + ((v.i >> 16) & 1u);
    return (u16)(r >> 16);
}
__device__ __forceinline__ float sigf(float x) { return 1.0f / (1.0f + __expf(-x)); }
__device__ __forceinline__ i32x4 mfma8(i32x4 a, i32x4 b, i32x4 c) {
    return __builtin_amdgcn_mfma_i32_16x16x64_i8(a, b, c, 0, 0, 0);
}
__device__ __forceinline__ f32x4 mfmabf(bf16x8 a, bf16x8 b, f32x4 c) {
    return __builtin_amdgcn_mfma_f32_16x16x32_bf16(a, b, c, 0, 0, 0);
}
__device__ __forceinline__ void qsplit(float v, float s, int& hi, int& lo) {
    float q = fminf(fmaxf(v * s, -QMAX), QMAX);
    int qi = (int)rintf(q);
    lo = ((qi + 128) & 255) - 128;
    hi = (qi - lo) >> 8;
}
__device__ __forceinline__ void gll16(const void* g, void* l) {
    __builtin_amdgcn_global_load_lds(
        (const __attribute__((address_space(1))) void*)g,
        (__attribute__((address_space(3))) void*)l, 16, 0, 0);
}

// ---------------- per-column max |U|
__global__ __launch_bounds__(256) void uscale_kernel(
    const float* __restrict__ U0, const float* __restrict__ U1,
    const float* __restrict__ U2, const float* __restrict__ U3,
    float* __restrict__ Uscale)
{
    int idx = blockIdx.x * 256 + threadIdx.x;
    if (idx < 4096) {
        int l = idx >> 10, col = idx & 1023;
        const float* U = (l==0)?U0:(l==1)?U1:(l==2)?U2:U3;
        float m = 0.f;
        for (int k = 0; k < 256; ++k) m = fmaxf(m, fabsf(U[k*1024 + col]));
        Uscale[idx] = m;
    }
}

// ---------------- pack U to i8 hi/lo in MFMA-fragment order (R2-verbatim layout)
// Upk per lstm 512KB: byte = cb*8192 + kt*2048 + half*1024 + lane*16 + i
__global__ __launch_bounds__(256) void upack_kernel(
    const float* __restrict__ U0, const float* __restrict__ U1,
    const float* __restrict__ U2, const float* __restrict__ U3,
    const float* __restrict__ Uscale, u8* __restrict__ Upk)
{
    int idx = blockIdx.x * 256 + threadIdx.x;      // one u32 per thread, < 524288
    int byte = idx * 4;
    int l = byte >> 19; int off = byte & 524287;
    int cb = off >> 13; int r1 = off & 8191;
    int kt = r1 >> 11;  int r2 = r1 & 2047;
    int half = r2 >> 10; int lb = r2 & 1023;
    int lane = lb >> 4;  int i0 = lb & 15;
    const float* U = (l==0)?U0:(l==1)?U1:(l==2)?U2:U3;
    int col = cb*16 + (lane & 15);
    float s = QMAX / fmaxf(Uscale[l*1024 + col], 1e-30f);
    uint32_t w = 0;
    for (int j = 0; j < 4; ++j) {
        int k = kt*64 + (lane >> 4)*16 + i0 + j;
        int hi, lo; qsplit(U[k*1024 + col], s, hi, lo);
        int b = half ? lo : hi;
        w |= ((uint32_t)(b & 255)) << (8*j);
    }
    ((uint32_t*)Upk)[idx] = w;
}

// ---------------- W -> bf16 pair (hi + residual), [lstm][col][96] each, zero-padded k>=F
__global__ __launch_bounds__(256) void wpair_kernel(
    const float* __restrict__ W0, const float* __restrict__ W1,
    const float* __restrict__ W2, const float* __restrict__ W3,
    u16* __restrict__ Wbh, u16* __restrict__ Wbl)
{
    int idx = blockIdx.x * 256 + threadIdx.x;      // < 393216
    int lstm = idx / 98304; int rem = idx - lstm*98304;
    int col = rem / 96; int k = rem - col*96;
    const int F = (lstm==0)?80:(lstm==1)?64:(lstm==2)?48:32;
    const float* W = (lstm==0)?W0:(lstm==1)?W1:(lstm==2)?W2:W3;
    float v = (k < F) ? W[k*1024 + col] : 0.f;
    u16 hb = f2bf(v);
    Wbh[idx] = hb;
    Wbl[idx] = f2bf(v - bf2f(hb));
}

// ---------------- z_x GEMM: zx[lstm][b][t_local][1024] i16 = (x@W + bias) * 2047
// one WG per (lstm,b); 4 waves, wave wv owns col-blocks [wv*16, wv*16+16)
__global__ __launch_bounds__(256) void zx_gemm_kernel(
    const float* __restrict__ x0, const float* __restrict__ x1,
    const float* __restrict__ x2, const float* __restrict__ x3,
    const float* __restrict__ bb0, const float* __restrict__ bb1,
    const float* __restrict__ bb2, const float* __restrict__ bb3,
    const u16* __restrict__ Wbh, const u16* __restrict__ Wbl,
    short* __restrict__ zxg, u8* __restrict__ maskb, int t0, int nt)
{
    const int lstm = blockIdx.x >> 7;
    const int b = blockIdx.x & 127;
    const int F = (lstm==0)?80:(lstm==1)?64:(lstm==2)?48:32;
    const int KT = (F + 31) >> 5;
    const float* xin  = (lstm==0)?x0:(lstm==1)?x1:(lstm==2)?x2:x3;
    const float* bias = (lstm==0)?bb0:(lstm==1)?bb1:(lstm==2)?bb2:bb3;

    const int tid = threadIdx.x, wv = tid >> 6, l = tid & 63, lg = l >> 4, ln = l & 15;
    const int rr = tid >> 4, cc = tid & 15;

    __shared__ u16 xh[16][104], xl[16][104];
    __shared__ u8 anyf[16][16];

    const int TT = nt >> 4;
    for (int tt = 0; tt < TT; ++tt) {
        const int tb = t0 + tt*16;
        // stage 16 rows of x as bf16 pair, compute mask
        bool any = false;
#pragma unroll
        for (int j = 0; j < 6; ++j) {
            int f = cc + 16*j;
            if (f < 96) {
                float v = (f < F) ? xin[((size_t)b*256 + tb + rr)*F + f] : 0.f;
                if (f < F) any = any || (v != -1.0f);
                u16 hb = f2bf(v);
                xh[rr][f] = hb;
                xl[rr][f] = f2bf(v - bf2f(hb));
            }
        }
        anyf[rr][cc] = any ? 1 : 0;
        __syncthreads();
        if (tid < 16) {
            int m = 0;
#pragma unroll
            for (int q = 0; q < 16; ++q) m |= anyf[tid][q];
            maskb[((size_t)(lstm*128 + b))*256 + tb + tid] = (u8)(m ? 1 : 0);
        }

        f32x4 acc[16];
#pragma unroll
        for (int cbi = 0; cbi < 16; ++cbi) acc[cbi] = (f32x4){0.f,0.f,0.f,0.f};

        for (int kt = 0; kt < KT; ++kt) {
            bf16x8 ah = *(const bf16x8*)&xh[ln][kt*32 + lg*8];
            bf16x8 al = *(const bf16x8*)&xl[ln][kt*32 + lg*8];
#pragma unroll
            for (int cbi = 0; cbi < 16; ++cbi) {
                int col = (wv*16 + cbi)*16 + ln;
                size_t wo = ((size_t)(lstm*1024) + col)*96 + kt*32 + lg*8;
                bf16x8 wh = *(const bf16x8*)(Wbh + wo);
                bf16x8 wl = *(const bf16x8*)(Wbl + wo);
                acc[cbi] = mfmabf(ah, wh, acc[cbi]);
                acc[cbi] = mfmabf(al, wh, acc[cbi]);
                acc[cbi] = mfmabf(ah, wl, acc[cbi]);
            }
        }
#pragma unroll
        for (int cbi = 0; cbi < 16; ++cbi) {
            int col = (wv*16 + cbi)*16 + ln;
            float bs = bias[col];
#pragma unroll
            for (int reg = 0; reg < 4; ++reg) {
                int tl = tt*16 + lg*4 + reg;     // C/D: row=(lane>>4)*4+reg, col=lane&15
                float z = acc[cbi][reg] + bs;
                int q = (int)rintf(fminf(fmaxf(z * ZSCL, -32767.f), 32767.f));
                zxg[((size_t)(lstm*128 + b)*nt + tl)*1024 + col] = (short)q;
            }
        }
        __syncthreads();
    }
}

// ---------------- recurrence: U-hi MFMA fragments resident in VGPRs, U-lo streamed from L2
template<int H>
__device__ __forceinline__ void do_half(
    const u8* __restrict__ Ubl1,            // Ub + l*16 + 1024 (half=1 base)
    const u8* qA0, const u8* qA1,
    const i32x4 (&UH)[32], const float (&cU)[8], const float (&rmax_)[4],
    int w, int lg, int ln, float zout[4][4])
{
    i32x4 aP[4], aX[4];
#pragma unroll
    for (int q = 0; q < 4; ++q) { aP[q] = (i32x4){0,0,0,0}; aX[q] = (i32x4){0,0,0,0}; }
#pragma unroll
    for (int kt = 0; kt < 4; ++kt) {
        i32x4 ul[4];
#pragma unroll
        for (int q = 0; q < 4; ++q) {
            const int ti = H*4 + q;
            const int cb = ((ti >> 1) * 16) + 2*w + (ti & 1);
            ul[q] = *(const i32x4*)(Ubl1 + (size_t)((cb*4 + kt)*2)*1024);
        }
        const int slot = ((kt*4 + lg) ^ ln);
        i32x4 hh = *(const i32x4*)(qA0 + ln*256 + slot*16);
        i32x4 hl = *(const i32x4*)(qA1 + ln*256 + slot*16);
#pragma unroll
        for (int q = 0; q < 4; ++q) {
            aP[q] = mfma8(hh, UH[(H*4+q)*4 + kt], aP[q]);
            aX[q] = mfma8(hl, UH[(H*4+q)*4 + kt], aX[q]);
            aX[q] = mfma8(hh, ul[q], aX[q]);
        }
    }
#pragma unroll
    for (int q = 0; q < 4; ++q)
#pragma unroll
        for (int rg = 0; rg < 4; ++rg)
            zout[q][rg] = (65536.f*(float)aP[q][rg] + 256.f*(float)aX[q][rg]) * cU[H*4+q] * rmax_[rg];
}

__global__ __launch_bounds__(512, 2) void lstm_rec_kernel(
    const u8* __restrict__ Upk, const short* __restrict__ zxg,
    const u8* __restrict__ maskb, const float* __restrict__ Uscale,
    float* __restrict__ c_state, float* __restrict__ h_state,
    u16* __restrict__ merged, int t0, int nt)
{
    const int bx = blockIdx.x;
    const int lstm = (bx & 7) >> 1;                       // XCD-grouped: lstm l on XCDs 2l,2l+1
    const int rb   = ((bx >> 3) << 1) | (bx & 1);
    const int b0 = rb * 16;

    const int tid = threadIdx.x;
    const int w = tid >> 6, l = tid & 63, lg = l >> 4, ln = l & 15;
    const u8* Ub = Upk + (size_t)lstm * 524288;
    const u8* Ubl = Ub + (size_t)l * 16;

    __shared__ short zx_lds[2][16][1024];   // 64KB, dbuf
    __shared__ u8 qA[2][16][256];           // [half][row][swizzled] 8KB
    __shared__ u8 mask_l[16][256];          // 4KB
    __shared__ float wmax[16][8];

    // preload mask for this chunk
    for (int i = tid; i < 4096; i += 512) {
        int r = i >> 8, s = i & 255;
        if (s < nt) mask_l[r][s] = maskb[((size_t)(lstm*128 + b0 + r))*256 + t0 + s];
    }

    // U-hi fragments -> registers (persistent)
    i32x4 UH[32];
#pragma unroll
    for (int ti = 0; ti < 8; ++ti)
#pragma unroll
        for (int kt = 0; kt < 4; ++kt) {
            const int cb = ((ti >> 1) * 16) + 2*w + (ti & 1);
            UH[ti*4 + kt] = *(const i32x4*)(Ubl + (size_t)((cb*4 + kt)*2)*1024);
        }

    const int u0 = 32*w + ln, u1 = u0 + 16;
    float cU[8];
#pragma unroll
    for (int ti = 0; ti < 8; ++ti) {
        int col = (ti >> 1)*256 + 32*w + 16*(ti & 1) + ln;
        cU[ti] = Uscale[lstm*1024 + col] * (1.0f/(QMAX*QMAX));
    }

    float c_[2][4], h_[2][4];
    if (t0 == 0) {
#pragma unroll
        for (int m = 0; m < 2; ++m)
#pragma unroll
            for (int rg = 0; rg < 4; ++rg) { c_[m][rg] = 0.f; h_[m][rg] = 0.f; }
    } else {
#pragma unroll
        for (int m = 0; m < 2; ++m)
#pragma unroll
            for (int rg = 0; rg < 4; ++rg) {
                size_t o = ((size_t)(lstm*128 + b0 + lg*4 + rg))*256 + (m==0?u0:u1);
                c_[m][rg] = c_state[o]; h_[m][rg] = h_state[o];
            }
    }

    // stage zx for s=0 into buf0
    {
#pragma unroll
        for (int j = 0; j < 4; ++j) {
            int c = j*512 + w*64 + l;
            int row = c >> 7, cb16 = c & 127;
            const u8* src = (const u8*)zxg + (((size_t)(lstm*128 + b0 + row)*nt + 0)*1024)*2 + (size_t)cb16*16;
            gll16(src, (u8*)&zx_lds[0][0][0] + (size_t)c*16);
        }
    }
    __syncthreads();

    for (int s = 0; s < nt; ++s) {
        // (1) cross-lane row max of current h (h >= 0)
#pragma unroll
        for (int rg = 0; rg < 4; ++rg) {
            float v = fmaxf(h_[0][rg], h_[1][rg]);
            v = fmaxf(v, __shfl_xor(v, 1));
            v = fmaxf(v, __shfl_xor(v, 2));
            v = fmaxf(v, __shfl_xor(v, 4));
            v = fmaxf(v, __shfl_xor(v, 8));
            if (ln == 0) wmax[lg*4 + rg][w] = v;
        }
        __syncthreads();   // B1

        // (3) row max over waves, quantize h -> qA (R2-verbatim swizzle)
        float rmax_[4];
#pragma unroll
        for (int rg = 0; rg < 4; ++rg) {
            const int r = lg*4 + rg;
            float4 p0 = *(const float4*)&wmax[r][0];
            float4 p1 = *(const float4*)&wmax[r][4];
            float rm = fmaxf(fmaxf(fmaxf(p0.x,p0.y),fmaxf(p0.z,p0.w)),
                             fmaxf(fmaxf(p1.x,p1.y),fmaxf(p1.z,p1.w)));
            rmax_[rg] = rm;
            float qs = QMAX / fmaxf(rm, 1e-30f);
#pragma unroll
            for (int m = 0; m < 2; ++m) {
                const int u = (m == 0) ? u0 : u1;
                int hi, lo; qsplit(h_[m][rg], qs, hi, lo);
                int pos = (((u >> 4) ^ r) << 4) | (u & 15);
                qA[0][r][pos] = (u8)hi;
                qA[1][r][pos] = (u8)lo;
            }
        }
        __syncthreads();   // B2: qA visible

        // (5a) prefetch zx for s+1 (lands before next B1; consumed next epilogue)
        if (s + 1 < nt) {
            const int buf = (s + 1) & 1;
#pragma unroll
            for (int j = 0; j < 4; ++j) {
                int c = j*512 + w*64 + l;
                int row = c >> 7, cb16 = c & 127;
                const u8* src = (const u8*)zxg + (((size_t)(lstm*128 + b0 + row)*nt + (s+1))*1024)*2 + (size_t)cb16*16;
                gll16(src, (u8*)&zx_lds[buf][0][0] + (size_t)c*16);
            }
        }

        // (5b) h @ U via resident U-hi + streamed U-lo
        float zh0[4][4], zh1[4][4];
        do_half<0>(Ubl + 1024, &qA[0][0][0], &qA[1][0][0], UH, cU, rmax_, w, lg, ln, zh0);
        do_half<1>(Ubl + 1024, &qA[0][0][0], &qA[1][0][0], UH, cU, rmax_, w, lg, ln, zh1);

        // (6) gates + state update + merged store
#pragma unroll
        for (int rg = 0; rg < 4; ++rg) {
            const int r = lg*4 + rg;
            const int mk = mask_l[r][s];
            const short* zrow = &zx_lds[s & 1][r][0];
#pragma unroll
            for (int m = 0; m < 2; ++m) {
                const int u = (m == 0) ? u0 : u1;
                float zi = (float)zrow[      u] * (1.0f/ZSCL) + zh0[0+m][rg];
                float zf = (float)zrow[256 + u] * (1.0f/ZSCL) + zh0[2+m][rg];
                float zg = (float)zrow[512 + u] * (1.0f/ZSCL) + zh1[0+m][rg];
                float zo = (float)zrow[768 + u] * (1.0f/ZSCL) + zh1[2+m][rg];
                float ig = sigf(zi), fg = sigf(zf), og = sigf(zo);
                float gg = fmaxf(zg, 0.f);
                float cn = fg * c_[m][rg] + ig * gg;
                float hn = og * fmaxf(cn, 0.f);
                if (!mk) { cn = c_[m][rg]; hn = h_[m][rg]; }
                c_[m][rg] = cn; h_[m][rg] = hn;
                merged[((size_t)(b0 + r)*256 + (t0 + s))*1024 + lstm*256 + u] = f2bf(hn);
            }
        }
    }

    if (t0 + nt < 256) {
#pragma unroll
        for (int m = 0; m < 2; ++m)
#pragma unroll
            for (int rg = 0; rg < 4; ++rg) {
                size_t o = ((size_t)(lstm*128 + b0 + lg*4 + rg))*256 + (m==0?u0:u1);
                c_state[o] = c_[m][rg]; h_state[o] = h_[m][rg];
            }
    }
}

// ---------------- attention + output head (R2 verbatim)
__global__ __launch_bounds__(256) void attn_kernel(
    const u16* __restrict__ merged,
    const float* __restrict__ w_att, const float* __restrict__ b_att,
    const float* __restrict__ w_out, const float* __restrict__ b_out,
    float* __restrict__ out)
{
    const int b = blockIdx.x;
    const int tid = threadIdx.x;
    const int wv = tid >> 6;
    const int l = tid & 63;

    __shared__ float watt_s[1024];
    __shared__ float wout_s[1024];
    __shared__ float sc[256];
    __shared__ float red[8];

    for (int i = tid; i < 1024; i += 256) {
        watt_s[i] = w_att[i];
        wout_s[i] = w_out[i];
    }
    __syncthreads();

    const float batt = b_att[0];

    for (int tt = wv; tt < 256; tt += 4) {
        const u16* row = merged + ((size_t)b * 256 + tt) * 1024 + l * 16;
        uint4 q0 = *(const uint4*)(row);
        uint4 q1 = *(const uint4*)(row + 8);
        const float* wp = &watt_s[l * 16];
        uint32_t qa[8] = {q0.x, q0.y, q0.z, q0.w, q1.x, q1.y, q1.z, q1.w};
        float s = 0.f;
#pragma unroll
        for (int i = 0; i < 8; ++i) {
            s += bf2f((u16)(qa[i] & 0xffffu)) * wp[2 * i];
            s += bf2f((u16)(qa[i] >> 16)) * wp[2 * i + 1];
        }
#pragma unroll
        for (int o = 32; o > 0; o >>= 1) s += __shfl_xor(s, o);
        if (l == 0) sc[tt] = tanhf(s + batt);
    }
    __syncthreads();

    float v = sc[tid];
    float mx = v;
#pragma unroll
    for (int o = 32; o > 0; o >>= 1) mx = fmaxf(mx, __shfl_xor(mx, o));
    if (l == 0) red[wv] = mx;
    __syncthreads();
    mx = fmaxf(fmaxf(red[0], red[1]), fmaxf(red[2], red[3]));
    float p = __expf(v - mx);
    float sm = p;
#pragma unroll
    for (int o = 32; o > 0; o >>= 1) sm += __shfl_xor(sm, o);
    if (l == 0) red[4 + wv] = sm;
    __syncthreads();
    sm = red[4] + red[5] + red[6] + red[7];
    p /= sm;
    sc[tid] = p;
    __syncthreads();

    const int d0 = tid * 4;
    float a0 = 0.f, a1 = 0.f, a2 = 0.f, a3 = 0.f;
    for (int t = 0; t < 256; ++t) {
        float pp = sc[t];
        const u16* mp = merged + ((size_t)b * 256 + t) * 1024 + d0;
        ushort4 q = *(const ushort4*)mp;
        a0 += pp * bf2f(q.x);
        a1 += pp * bf2f(q.y);
        a2 += pp * bf2f(q.z);
        a3 += pp * bf2f(q.w);
    }
    float part = a0 * wout_s[d0] + a1 * wout_s[d0 + 1] + a2 * wout_s[d0 + 2] + a3 * wout_s[d0 + 3];
#pragma unroll
    for (int o = 32; o > 0; o >>= 1) part += __shfl_xor(part, o);
    __syncthreads();
    if (l == 0) red[wv] = part;
    __syncthreads();
    if (tid == 0) {
        float tot = red[0] + red[1] + red[2] + red[3] + b_out[0];
        out[b] = 1.0f / (1.0f + __expf(-tot));
    }
}

extern "C" void kernel_launch(void* const* d_in, const int* in_sizes, int n_in,
                              void* d_out, int out_size, void* d_ws, size_t ws_size,
                              hipStream_t stream) {
    (void)in_sizes; (void)n_in; (void)out_size;
    const float* x[4]; const float* W[4]; const float* U[4]; const float* bb[4];
    for (int i = 0; i < 4; ++i) {
        x[i]  = (const float*)d_in[4 * i + 0];
        W[i]  = (const float*)d_in[4 * i + 1];
        U[i]  = (const float*)d_in[4 * i + 2];
        bb[i] = (const float*)d_in[4 * i + 3];
    }
    const float* w_att = (const float*)d_in[16];
    const float* b_att = (const float*)d_in[17];
    const float* w_out = (const float*)d_in[18];
    const float* b_out = (const float*)d_in[19];

    u8* base = (u8*)d_ws;
    size_t off = 0;
    auto alloc = [&](size_t n) { u8* p = base + off; off += (n + 255) & ~(size_t)255; return p; };
    u16*   merged  = (u16*)  alloc(67108864);        // [128][256][1024] bf16
    u8*    Upk     =         alloc(2097152);         // i8 hi/lo frags
    u16*   Wbh     = (u16*)  alloc(786432);          // bf16 pair
    u16*   Wbl     = (u16*)  alloc(786432);
    float* Uscale  = (float*)alloc(16384);
    u8*    maskb   =         alloc(131072);
    float* c_state = (float*)alloc(524288);
    float* h_state = (float*)alloc(524288);
    size_t fixed = off;

    int nt = 256;                                     // zx chunk = nt MB; adapt to ws_size
    while (nt > 16 && fixed + (size_t)nt * 1048576 > ws_size) nt >>= 1;
    short* zxg = (short*)alloc((size_t)nt * 1048576);

    uscale_kernel<<<dim3(16),   dim3(256), 0, stream>>>(U[0], U[1], U[2], U[3], Uscale);
    upack_kernel <<<dim3(2048), dim3(256), 0, stream>>>(U[0], U[1], U[2], U[3], Uscale, Upk);
    wpair_kernel <<<dim3(1536), dim3(256), 0, stream>>>(W[0], W[1], W[2], W[3], Wbh, Wbl);

    for (int t0 = 0; t0 < 256; t0 += nt) {
        zx_gemm_kernel<<<dim3(512), dim3(256), 0, stream>>>(
            x[0], x[1], x[2], x[3], bb[0], bb[1], bb[2], bb[3],
            Wbh, Wbl, zxg, maskb, t0, nt);
        lstm_rec_kernel<<<dim3(32), dim3(512), 0, stream>>>(
            Upk, zxg, maskb, Uscale, c_state, h_state, merged, t0, nt);
    }

    attn_kernel<<<dim3(128), dim3(256), 0, stream>>>(
        merged, w_att, b_att, w_out, b_out, (float*)d_out);
}

// Round 4
// 3445.703 us; speedup vs baseline: 1.6717x; 1.2085x over previous
//
#include <hip/hip_runtime.h>
#include <stdint.h>

typedef __attribute__((ext_vector_type(4))) int   i32x4;
typedef __attribute__((ext_vector_type(4))) float f32x4;
typedef __attribute__((ext_vector_type(8))) short bf16x8;
typedef unsigned short u16;
typedef unsigned char  u8;

#define QMAX 32512.0f
#define ZSCL 2047.0f
#define INV_ZSCL (1.0f/2047.0f)

__device__ __forceinline__ float bf2f(u16 u) {
    union { uint32_t i; float f; } v; v.i = ((uint32_t)u) << 16; return v.f;
}
__device__ __forceinline__ u16 f2bf(float f) {
    union { float f; uint32_t i; } v; v.f = f;
    uint32_t r = v.i + 0x7fffu + ((v.i >> 16) & 1u);
    return (u16)(r >> 16);
}
__device__ __forceinline__ float sigf(float x) { return 1.0f / (1.0f + __expf(-x)); }
__device__ __forceinline__ i32x4 mfma8(i32x4 a, i32x4 b, i32x4 c) {
    return __builtin_amdgcn_mfma_i32_16x16x64_i8(a, b, c, 0, 0, 0);
}
__device__ __forceinline__ f32x4 mfmabf(bf16x8 a, bf16x8 b, f32x4 c) {
    return __builtin_amdgcn_mfma_f32_16x16x32_bf16(a, b, c, 0, 0, 0);
}
__device__ __forceinline__ void qsplit(float v, float s, int& hi, int& lo) {
    float q = fminf(fmaxf(v * s, -QMAX), QMAX);
    int qi = (int)rintf(q);
    lo = ((qi + 128) & 255) - 128;
    hi = (qi - lo) >> 8;
}
__device__ __forceinline__ void gll16(const void* g, void* l) {
    __builtin_amdgcn_global_load_lds(
        (const __attribute__((address_space(1))) void*)g,
        (__attribute__((address_space(3))) void*)l, 16, 0, 0);
}
// lgkm-only barrier: LDS producer/consumer sync WITHOUT draining vmcnt
// (keeps global_load_lds prefetch + stores in flight across the barrier)
__device__ __forceinline__ void bar_lgk() {
    __builtin_amdgcn_sched_barrier(0);
    asm volatile("s_waitcnt lgkmcnt(0)" ::: "memory");
    __builtin_amdgcn_s_barrier();
    __builtin_amdgcn_sched_barrier(0);
}

// ---------------- per-column max |U|
__global__ __launch_bounds__(256) void uscale_kernel(
    const float* __restrict__ U0, const float* __restrict__ U1,
    const float* __restrict__ U2, const float* __restrict__ U3,
    float* __restrict__ Uscale)
{
    int idx = blockIdx.x * 256 + threadIdx.x;
    if (idx < 4096) {
        int l = idx >> 10, col = idx & 1023;
        const float* U = (l==0)?U0:(l==1)?U1:(l==2)?U2:U3;
        float m = 0.f;
        for (int k = 0; k < 256; ++k) m = fmaxf(m, fabsf(U[k*1024 + col]));
        Uscale[idx] = m;
    }
}

// ---------------- pack U to i8 hi/lo, PHASE layout:
// Upk2[lstm][phase 16][w 8][m 2][half 2][lane 64][16B]; phase = kt*4+g;
// cb = g*16+2w+m; col = cb*16+(lane&15); k = kt*64+(lane>>4)*16+i
__global__ __launch_bounds__(256) void upack_kernel(
    const float* __restrict__ U0, const float* __restrict__ U1,
    const float* __restrict__ U2, const float* __restrict__ U3,
    const float* __restrict__ Uscale, u8* __restrict__ Upk2)
{
    int idx = blockIdx.x * 256 + threadIdx.x;      // one u32 per thread, < 524288
    int byte = idx * 4;
    int l = byte >> 19;  int off = byte & 0x7FFFF;
    int p = off >> 15;   int r2 = off & 0x7FFF;
    int w = r2 >> 12;    int r3 = r2 & 0xFFF;
    int m = r3 >> 11;    int half = (r3 >> 10) & 1;
    int lb = r3 & 1023;
    int lane = lb >> 4;  int ib = lb & 15;
    int g = p & 3, kt = p >> 2;
    const float* U = (l==0)?U0:(l==1)?U1:(l==2)?U2:U3;
    int cb = g*16 + 2*w + m;
    int col = cb*16 + (lane & 15);
    float s = QMAX / fmaxf(Uscale[l*1024 + col], 1e-30f);
    uint32_t wd = 0;
    for (int j = 0; j < 4; ++j) {
        int k = kt*64 + (lane >> 4)*16 + ib + j;
        int hi, lo; qsplit(U[k*1024 + col], s, hi, lo);
        int b = half ? lo : hi;
        wd |= ((uint32_t)(b & 255)) << (8*j);
    }
    ((uint32_t*)Upk2)[idx] = wd;
}

// ---------------- W -> bf16 pair (hi + residual), [lstm][col][96], zero-padded k>=F
__global__ __launch_bounds__(256) void wpair_kernel(
    const float* __restrict__ W0, const float* __restrict__ W1,
    const float* __restrict__ W2, const float* __restrict__ W3,
    u16* __restrict__ Wbh, u16* __restrict__ Wbl)
{
    int idx = blockIdx.x * 256 + threadIdx.x;      // < 393216
    int lstm = idx / 98304; int rem = idx - lstm*98304;
    int col = rem / 96; int k = rem - col*96;
    const int F = (lstm==0)?80:(lstm==1)?64:(lstm==2)?48:32;
    const float* W = (lstm==0)?W0:(lstm==1)?W1:(lstm==2)?W2:W3;
    float v = (k < F) ? W[k*1024 + col] : 0.f;
    u16 hb = f2bf(v);
    Wbh[idx] = hb;
    Wbl[idx] = f2bf(v - bf2f(hb));
}

// ---------------- z_x GEMM -> i16, REC-THREAD layout:
// zxg[(lstm*128+b)*nt + t][1024 shorts]; slot = (w*16+ln)*8 + g*2 + m
// 8 waves, wave w owns cb = g*16+2w+m (ti = g*2+m), so each thread's 8 gate
// values per row are one contiguous 16B store (coalesced 256B runs).
__global__ __launch_bounds__(512) void zx_gemm_kernel(
    const float* __restrict__ x0, const float* __restrict__ x1,
    const float* __restrict__ x2, const float* __restrict__ x3,
    const float* __restrict__ bb0, const float* __restrict__ bb1,
    const float* __restrict__ bb2, const float* __restrict__ bb3,
    const u16* __restrict__ Wbh, const u16* __restrict__ Wbl,
    short* __restrict__ zxg, u8* __restrict__ maskb, int t0, int nt)
{
    const int lstm = blockIdx.x >> 7;
    const int b = blockIdx.x & 127;
    const int F = (lstm==0)?80:(lstm==1)?64:(lstm==2)?48:32;
    const int KT = (F + 31) >> 5;
    const float* xin  = (lstm==0)?x0:(lstm==1)?x1:(lstm==2)?x2:x3;
    const float* bias = (lstm==0)?bb0:(lstm==1)?bb1:(lstm==2)?bb2:bb3;

    const int tid = threadIdx.x;
    const int w = tid >> 6, l = tid & 63, lg = l >> 4, ln = l & 15;
    const int rr = tid >> 5, cc = tid & 31;

    __shared__ u16 xh[16][104], xl[16][104];
    __shared__ u8 anyf[16][32];

    float bv[8];
    size_t wo_base[8];
#pragma unroll
    for (int ti = 0; ti < 8; ++ti) {
        int g = ti >> 1, m = ti & 1;
        int col = (g*16 + 2*w + m)*16 + ln;
        bv[ti] = bias[col];
        wo_base[ti] = ((size_t)(lstm*1024) + col)*96 + lg*8;
    }

    const int TT = nt >> 4;
    for (int tt = 0; tt < TT; ++tt) {
        const int tb = t0 + tt*16;
        bool any = false;
#pragma unroll
        for (int j = 0; j < 3; ++j) {
            int f = cc + 32*j;
            float v = (f < F) ? xin[((size_t)b*256 + tb + rr)*F + f] : 0.f;
            if (f < F) any = any || (v != -1.0f);
            u16 hb = f2bf(v);
            xh[rr][f] = hb;
            xl[rr][f] = f2bf(v - bf2f(hb));
        }
        anyf[rr][cc] = any ? 1 : 0;
        __syncthreads();
        if (tid < 16) {
            int mm = 0;
#pragma unroll
            for (int q = 0; q < 32; ++q) mm |= anyf[tid][q];
            maskb[((size_t)(lstm*128 + b))*256 + tb + tid] = (u8)(mm ? 1 : 0);
        }

        f32x4 acc[8];
#pragma unroll
        for (int ti = 0; ti < 8; ++ti) acc[ti] = (f32x4){0.f,0.f,0.f,0.f};

        for (int kt = 0; kt < KT; ++kt) {
            bf16x8 ah = *(const bf16x8*)&xh[ln][kt*32 + lg*8];
            bf16x8 al = *(const bf16x8*)&xl[ln][kt*32 + lg*8];
#pragma unroll
            for (int ti = 0; ti < 8; ++ti) {
                const u16* wp = Wbh + wo_base[ti] + kt*32;
                const u16* wq = Wbl + wo_base[ti] + kt*32;
                bf16x8 wh = *(const bf16x8*)wp;
                bf16x8 wl = *(const bf16x8*)wq;
                acc[ti] = mfmabf(ah, wh, acc[ti]);
                acc[ti] = mfmabf(al, wh, acc[ti]);
                acc[ti] = mfmabf(ah, wl, acc[ti]);
            }
        }
#pragma unroll
        for (int reg = 0; reg < 4; ++reg) {
            int tl = tt*16 + lg*4 + reg;
            uint32_t d[4];
#pragma unroll
            for (int g = 0; g < 4; ++g) {
                int q0 = (int)rintf(fminf(fmaxf((acc[2*g  ][reg] + bv[2*g  ]) * ZSCL, -32767.f), 32767.f));
                int q1 = (int)rintf(fminf(fmaxf((acc[2*g+1][reg] + bv[2*g+1]) * ZSCL, -32767.f), 32767.f));
                d[g] = ((uint32_t)q0 & 0xffffu) | (((uint32_t)q1 & 0xffffu) << 16);
            }
            i32x4 out = { (int)d[0], (int)d[1], (int)d[2], (int)d[3] };
            short* dst = zxg + ((size_t)(lstm*128 + b)*nt + tl)*1024 + (w*16 + ln)*8;
            *(i32x4*)dst = out;
        }
        __syncthreads();
    }
}

// ---------------- recurrence: 32 WGs (same-lstm per XCD), 512 thr (8 waves).
// U streamed via wave-private global_load_lds phases (16 x 32KB; 2 permanent,
// 14 through a 2-buffer ring), counted vmcnt, lgkm-only barriers. zx in regs.
__global__ __launch_bounds__(512, 2) void lstm_rec_kernel(
    const u8* __restrict__ Upk2, const short* __restrict__ zxg,
    const u8* __restrict__ maskb, const float* __restrict__ Uscale,
    float* __restrict__ c_state, float* __restrict__ h_state,
    u16* __restrict__ merged, int t0, int nt)
{
    const int bx = blockIdx.x;
    const int lstm = (bx & 7) >> 1;                 // XCD-grouped: lstm l on XCDs 2l,2l+1
    const int rb   = ((bx >> 3) << 1) | (bx & 1);
    const int b0 = rb * 16;

    const int tid = threadIdx.x;
    const int w = tid >> 6, l = tid & 63, lg = l >> 4, ln = l & 15;
    const u8* Ub = Upk2 + (size_t)lstm * (16*32768);

    __shared__ u8 perm[2][8][4096];      // 64KB : phases 0,1 (kt0,g0 / kt0,g1)
    __shared__ u8 ring[2][8][4096];      // 64KB : stream double-buffer
    __shared__ u8 qA[2][16][256];        // 8KB  : h quantized hi/lo, swizzled
    __shared__ u8 mask_l[16][256];       // 4KB
    __shared__ float wmax[16][8];

    // ---- init: permanent phases + mask
#pragma unroll
    for (int p = 0; p < 2; ++p)
#pragma unroll
        for (int j = 0; j < 4; ++j)
            gll16(Ub + (size_t)p*32768 + (size_t)w*4096 + (size_t)j*1024 + (size_t)l*16,
                  &perm[p][w][j*1024 + l*16]);
    for (int i = tid; i < 4096; i += 512) {
        int r = i >> 8, s = i & 255;
        mask_l[r][s] = (s < nt) ? maskb[((size_t)(lstm*128 + b0 + r))*256 + t0 + s] : (u8)1;
    }
    __syncthreads();   // full drain once (perm gll + mask)

    const int u0 = 32*w + ln, u1 = u0 + 16;
    float cU[8];
#pragma unroll
    for (int ti = 0; ti < 8; ++ti) {
        int col = (ti >> 1)*256 + 32*w + 16*(ti & 1) + ln;
        cU[ti] = Uscale[lstm*1024 + col] * (1.0f/(QMAX*QMAX));
    }

    float c_[2][4], h_[2][4];
    if (t0 == 0) {
#pragma unroll
        for (int m = 0; m < 2; ++m)
#pragma unroll
            for (int rg = 0; rg < 4; ++rg) { c_[m][rg] = 0.f; h_[m][rg] = 0.f; }
    } else {
#pragma unroll
        for (int m = 0; m < 2; ++m)
#pragma unroll
            for (int rg = 0; rg < 4; ++rg) {
                size_t o = ((size_t)(lstm*128 + b0 + lg*4 + rg))*256 + (m==0?u0:u1);
                c_[m][rg] = c_state[o]; h_[m][rg] = h_state[o];
            }
    }

    u8* rw0 = &ring[0][w][0];
    u8* rw1 = &ring[1][w][0];
    const u8* qA0 = &qA[0][ln][0];
    const u8* qA1 = &qA[1][ln][0];
    const short* zxb = zxg + ((size_t)(lstm*128 + b0)) * nt * 1024;
    u16* mgb = merged + (size_t)b0 * 256 * 1024 + (size_t)lstm * 256;

    auto STAGE = [&](int qph, u8* dstw) {     // stage stream-index qph (data phase qph+2)
        const u8* src = Ub + (size_t)(qph + 2) * 32768 + (size_t)w * 4096 + (size_t)l * 16;
#pragma unroll
        for (int j = 0; j < 4; ++j)
            gll16(src + j*1024, dstw + j*1024 + l*16);
    };

    i32x4 zA[4], zB[4];
    // preload zx for s=0
#pragma unroll
    for (int rg = 0; rg < 4; ++rg)
        zA[rg] = *(const i32x4*)(zxb + ((size_t)(lg*4+rg)*nt + 0)*1024 + (w*16+ln)*8);
    // prologue: first two stream phases in flight
    STAGE(0, rw0);
    STAGE(1, rw1);

    auto STEP = [&](int s, i32x4 (&zc)[4], i32x4 (&zn)[4]) {
        // prefetch zx(s+1) into registers (consumed next step; HBM/L3 latency hidden)
        if (s + 1 < nt) {
#pragma unroll
            for (int rg = 0; rg < 4; ++rg)
                zn[rg] = *(const i32x4*)(zxb + ((size_t)(lg*4+rg)*nt + (s+1))*1024 + (w*16+ln)*8);
        }
        // (1) per-row wave max of h (h >= 0)
#pragma unroll
        for (int rg = 0; rg < 4; ++rg) {
            float v = fmaxf(h_[0][rg], h_[1][rg]);
            v = fmaxf(v, __shfl_xor(v, 1));
            v = fmaxf(v, __shfl_xor(v, 2));
            v = fmaxf(v, __shfl_xor(v, 4));
            v = fmaxf(v, __shfl_xor(v, 8));
            if (ln == 0) wmax[lg*4 + rg][w] = v;
        }
        bar_lgk();   // B1 (lgkm only: gll ring prefetch stays in flight)

        // (2) global row max -> quantize h into qA (R3-verbatim swizzle)
        float rmax_[4];
#pragma unroll
        for (int rg = 0; rg < 4; ++rg) {
            const int r = lg*4 + rg;
            float4 p0 = *(const float4*)&wmax[r][0];
            float4 p1 = *(const float4*)&wmax[r][4];
            float rm = fmaxf(fmaxf(fmaxf(p0.x,p0.y),fmaxf(p0.z,p0.w)),
                             fmaxf(fmaxf(p1.x,p1.y),fmaxf(p1.z,p1.w)));
            rmax_[rg] = rm;
            float qs = QMAX / fmaxf(rm, 1e-30f);
#pragma unroll
            for (int m = 0; m < 2; ++m) {
                const int u = (m == 0) ? u0 : u1;
                int hi, lo; qsplit(h_[m][rg], qs, hi, lo);
                int pos = (((u >> 4) ^ r) << 4) | (u & 15);
                qA[0][r][pos] = (u8)hi;
                qA[1][r][pos] = (u8)lo;
            }
        }
        bar_lgk();   // B2: qA visible

        // (3) h @ U over 16 phases; phase p = kt*4+g
        i32x4 aP[8], aX[8];
#pragma unroll
        for (int ti = 0; ti < 8; ++ti) { aP[ti] = (i32x4){0,0,0,0}; aX[ti] = (i32x4){0,0,0,0}; }

        i32x4 hh, hl;
        {
            int slot = (0*4 + lg) ^ ln;
            hh = *(const i32x4*)(qA0 + slot*16);
            hl = *(const i32x4*)(qA1 + slot*16);
        }
        // permanent phases 0,1
#pragma unroll
        for (int p = 0; p < 2; ++p) {
            const u8* src = &perm[p][w][0];
#pragma unroll
            for (int m = 0; m < 2; ++m) {
                i32x4 bh = *(const i32x4*)(src + m*2048 +        l*16);
                i32x4 bl = *(const i32x4*)(src + m*2048 + 1024 + l*16);
                aP[2*p+m] = mfma8(hh, bh, aP[2*p+m]);
                aX[2*p+m] = mfma8(hl, bh, aX[2*p+m]);
                aX[2*p+m] = mfma8(hh, bl, aX[2*p+m]);
            }
        }
        // streamed phases 2..15 (stream index q = p-2)
#pragma unroll
        for (int q = 0; q < 14; ++q) {
            const int p = q + 2, g = p & 3, kt = p >> 2;
            if (g == 0) {   // new kt block: reload A-fragment
                int slot = (kt*4 + lg) ^ ln;
                hh = *(const i32x4*)(qA0 + slot*16);
                hl = *(const i32x4*)(qA1 + slot*16);
            }
            asm volatile("s_waitcnt vmcnt(4)" ::: "memory");   // ring[q&1] data landed
            u8* src = (q & 1) ? rw1 : rw0;
#pragma unroll
            for (int m = 0; m < 2; ++m) {
                i32x4 bh = *(const i32x4*)(src + m*2048 +        l*16);
                i32x4 bl = *(const i32x4*)(src + m*2048 + 1024 + l*16);
                aP[2*g+m] = mfma8(hh, bh, aP[2*g+m]);
                aX[2*g+m] = mfma8(hl, bh, aX[2*g+m]);
                aX[2*g+m] = mfma8(hh, bl, aX[2*g+m]);
            }
            // refill same buffer with the next-needed phase (wraps to next step)
            asm volatile("s_waitcnt lgkmcnt(0)" ::: "memory"); // ring reads done before overwrite
            int tq = q + 2; if (tq >= 14) tq -= 14;
            STAGE(tq, src);
        }

        // (4) gates + state update + merged store
#pragma unroll
        for (int rg = 0; rg < 4; ++rg) {
            const int r = lg*4 + rg;
            const int mk = mask_l[r][s];
            const i32x4 zv = zc[rg];
#pragma unroll
            for (int m = 0; m < 2; ++m) {
                const int u = (m == 0) ? u0 : u1;
                float zi = (float)(short)(m ? ((uint32_t)zv[0] >> 16) : ((uint32_t)zv[0] & 0xffffu)) * INV_ZSCL
                         + (65536.f*(float)aP[0+m][rg] + 256.f*(float)aX[0+m][rg]) * cU[0+m] * rmax_[rg];
                float zf = (float)(short)(m ? ((uint32_t)zv[1] >> 16) : ((uint32_t)zv[1] & 0xffffu)) * INV_ZSCL
                         + (65536.f*(float)aP[2+m][rg] + 256.f*(float)aX[2+m][rg]) * cU[2+m] * rmax_[rg];
                float zg = (float)(short)(m ? ((uint32_t)zv[2] >> 16) : ((uint32_t)zv[2] & 0xffffu)) * INV_ZSCL
                         + (65536.f*(float)aP[4+m][rg] + 256.f*(float)aX[4+m][rg]) * cU[4+m] * rmax_[rg];
                float zo = (float)(short)(m ? ((uint32_t)zv[3] >> 16) : ((uint32_t)zv[3] & 0xffffu)) * INV_ZSCL
                         + (65536.f*(float)aP[6+m][rg] + 256.f*(float)aX[6+m][rg]) * cU[6+m] * rmax_[rg];
                float ig = sigf(zi), fg = sigf(zf), og = sigf(zo);
                float gg = fmaxf(zg, 0.f);
                float cn = fg * c_[m][rg] + ig * gg;
                float hn = og * fmaxf(cn, 0.f);
                if (!mk) { cn = c_[m][rg]; hn = h_[m][rg]; }
                c_[m][rg] = cn; h_[m][rg] = hn;
                mgb[((size_t)r * 256 + (t0 + s)) * 1024 + u] = f2bf(hn);
            }
        }
    };

    for (int s2 = 0; s2 < nt; s2 += 2) {
        STEP(s2,     zA, zB);
        STEP(s2 + 1, zB, zA);
    }

    asm volatile("s_waitcnt vmcnt(0)" ::: "memory");   // drain trailing ring glls

    if (t0 + nt < 256) {
#pragma unroll
        for (int m = 0; m < 2; ++m)
#pragma unroll
            for (int rg = 0; rg < 4; ++rg) {
                size_t o = ((size_t)(lstm*128 + b0 + lg*4 + rg))*256 + (m==0?u0:u1);
                c_state[o] = c_[m][rg]; h_state[o] = h_[m][rg];
            }
    }
}

// ---------------- attention + output head (R2/R3 verbatim)
__global__ __launch_bounds__(256) void attn_kernel(
    const u16* __restrict__ merged,
    const float* __restrict__ w_att, const float* __restrict__ b_att,
    const float* __restrict__ w_out, const float* __restrict__ b_out,
    float* __restrict__ out)
{
    const int b = blockIdx.x;
    const int tid = threadIdx.x;
    const int wv = tid >> 6;
    const int l = tid & 63;

    __shared__ float watt_s[1024];
    __shared__ float wout_s[1024];
    __shared__ float sc[256];
    __shared__ float red[8];

    for (int i = tid; i < 1024; i += 256) {
        watt_s[i] = w_att[i];
        wout_s[i] = w_out[i];
    }
    __syncthreads();

    const float batt = b_att[0];

    for (int tt = wv; tt < 256; tt += 4) {
        const u16* row = merged + ((size_t)b * 256 + tt) * 1024 + l * 16;
        uint4 q0 = *(const uint4*)(row);
        uint4 q1 = *(const uint4*)(row + 8);
        const float* wp = &watt_s[l * 16];
        uint32_t qa[8] = {q0.x, q0.y, q0.z, q0.w, q1.x, q1.y, q1.z, q1.w};
        float s = 0.f;
#pragma unroll
        for (int i = 0; i < 8; ++i) {
            s += bf2f((u16)(qa[i] & 0xffffu)) * wp[2 * i];
            s += bf2f((u16)(qa[i] >> 16)) * wp[2 * i + 1];
        }
#pragma unroll
        for (int o = 32; o > 0; o >>= 1) s += __shfl_xor(s, o);
        if (l == 0) sc[tt] = tanhf(s + batt);
    }
    __syncthreads();

    float v = sc[tid];
    float mx = v;
#pragma unroll
    for (int o = 32; o > 0; o >>= 1) mx = fmaxf(mx, __shfl_xor(mx, o));
    if (l == 0) red[wv] = mx;
    __syncthreads();
    mx = fmaxf(fmaxf(red[0], red[1]), fmaxf(red[2], red[3]));
    float p = __expf(v - mx);
    float sm = p;
#pragma unroll
    for (int o = 32; o > 0; o >>= 1) sm += __shfl_xor(sm, o);
    if (l == 0) red[4 + wv] = sm;
    __syncthreads();
    sm = red[4] + red[5] + red[6] + red[7];
    p /= sm;
    sc[tid] = p;
    __syncthreads();

    const int d0 = tid * 4;
    float a0 = 0.f, a1 = 0.f, a2 = 0.f, a3 = 0.f;
    for (int t = 0; t < 256; ++t) {
        float pp = sc[t];
        const u16* mp = merged + ((size_t)b * 256 + t) * 1024 + d0;
        ushort4 q = *(const ushort4*)mp;
        a0 += pp * bf2f(q.x);
        a1 += pp * bf2f(q.y);
        a2 += pp * bf2f(q.z);
        a3 += pp * bf2f(q.w);
    }
    float part = a0 * wout_s[d0] + a1 * wout_s[d0 + 1] + a2 * wout_s[d0 + 2] + a3 * wout_s[d0 + 3];
#pragma unroll
    for (int o = 32; o > 0; o >>= 1) part += __shfl_xor(part, o);
    __syncthreads();
    if (l == 0) red[wv] = part;
    __syncthreads();
    if (tid == 0) {
        float tot = red[0] + red[1] + red[2] + red[3] + b_out[0];
        out[b] = 1.0f / (1.0f + __expf(-tot));
    }
}

extern "C" void kernel_launch(void* const* d_in, const int* in_sizes, int n_in,
                              void* d_out, int out_size, void* d_ws, size_t ws_size,
                              hipStream_t stream) {
    (void)in_sizes; (void)n_in; (void)out_size;
    const float* x[4]; const float* W[4]; const float* U[4]; const float* bb[4];
    for (int i = 0; i < 4; ++i) {
        x[i]  = (const float*)d_in[4 * i + 0];
        W[i]  = (const float*)d_in[4 * i + 1];
        U[i]  = (const float*)d_in[4 * i + 2];
        bb[i] = (const float*)d_in[4 * i + 3];
    }
    const float* w_att = (const float*)d_in[16];
    const float* b_att = (const float*)d_in[17];
    const float* w_out = (const float*)d_in[18];
    const float* b_out = (const float*)d_in[19];

    u8* base = (u8*)d_ws;
    size_t off = 0;
    auto alloc = [&](size_t n) { u8* p = base + off; off += (n + 255) & ~(size_t)255; return p; };
    u16*   merged  = (u16*)  alloc(67108864);        // [128][256][1024] bf16
    u8*    Upk2    =         alloc(2097152);         // i8 hi/lo, phase layout
    u16*   Wbh     = (u16*)  alloc(786432);          // bf16 pair
    u16*   Wbl     = (u16*)  alloc(786432);
    float* Uscale  = (float*)alloc(16384);
    u8*    maskb   =         alloc(131072);
    float* c_state = (float*)alloc(524288);
    float* h_state = (float*)alloc(524288);
    size_t fixed = off;

    int nt = 256;                                     // zx chunk = nt MB; adapt to ws_size
    while (nt > 16 && fixed + (size_t)nt * 1048576 > ws_size) nt >>= 1;
    short* zxg = (short*)alloc((size_t)nt * 1048576);

    uscale_kernel<<<dim3(16),   dim3(256), 0, stream>>>(U[0], U[1], U[2], U[3], Uscale);
    upack_kernel <<<dim3(2048), dim3(256), 0, stream>>>(U[0], U[1], U[2], U[3], Uscale, Upk2);
    wpair_kernel <<<dim3(1536), dim3(256), 0, stream>>>(W[0], W[1], W[2], W[3], Wbh, Wbl);

    for (int t0 = 0; t0 < 256; t0 += nt) {
        zx_gemm_kernel<<<dim3(512), dim3(512), 0, stream>>>(
            x[0], x[1], x[2], x[3], bb[0], bb[1], bb[2], bb[3],
            Wbh, Wbl, zxg, maskb, t0, nt);
        lstm_rec_kernel<<<dim3(32), dim3(512), 0, stream>>>(
            Upk2, zxg, maskb, Uscale, c_state, h_state, merged, t0, nt);
    }

    attn_kernel<<<dim3(128), dim3(256), 0, stream>>>(
        merged, w_att, b_att, w_out, b_out, (float*)d_out);
}